// Round 13
// baseline (4336.676 us; speedup 1.0000x reference)
//
#include <hip/hip_runtime.h>
#include <hip/hip_bf16.h>

// ---------------- helpers ----------------
__device__ inline float fsig(float x) { return 1.0f / (1.0f + __expf(-x)); }
__device__ inline float ftanh(float x) {
    float ax = fabsf(x);
    float e = __expf(-2.0f * ax);
    float r = (1.0f - e) / (1.0f + e);
    return x >= 0.0f ? r : -r;
}
__device__ inline float felu(float x) { return x > 0.0f ? x : expm1f(x); }

typedef _Float16 h2_t __attribute__((ext_vector_type(2)));

__device__ inline unsigned int packh2(float a, float b) {
    unsigned short ua = __builtin_bit_cast(unsigned short, (_Float16)a);
    unsigned short ub = __builtin_bit_cast(unsigned short, (_Float16)b);
    return (unsigned int)ua | ((unsigned int)ub << 16);
}
__device__ inline unsigned short f16bits(float a) {
    return __builtin_bit_cast(unsigned short, (_Float16)a);
}

__device__ inline float dot2acc(unsigned int w, unsigned int h, float acc) {
#if __has_builtin(__builtin_amdgcn_fdot2)
    return __builtin_amdgcn_fdot2(__builtin_bit_cast(h2_t, w), __builtin_bit_cast(h2_t, h), acc, false);
#else
    _Float16 wlo = __builtin_bit_cast(_Float16, (unsigned short)(w & 0xffff));
    _Float16 whi = __builtin_bit_cast(_Float16, (unsigned short)(w >> 16));
    _Float16 hlo = __builtin_bit_cast(_Float16, (unsigned short)(h & 0xffff));
    _Float16 hhi = __builtin_bit_cast(_Float16, (unsigned short)(h >> 16));
    return acc + (float)wlo * (float)hlo + (float)whi * (float)hhi;
#endif
}

// ---------------- conv0: f32 in (CIN=4), f16 out ----------------
__global__ __launch_bounds__(256) void conv0_kernel(const float* __restrict__ in,
                                                    const float* __restrict__ wg,
                                                    const float* __restrict__ bias,
                                                    unsigned short* __restrict__ out) {
    constexpr int W = 84, OW = 42, PAD = 0, WP = W + 2;
    __shared__ float in_s[3 * WP * 4];
    constexpr int NQ = 3 * WP;
    const int tid = threadIdx.x;
    const int oy = blockIdx.x;
    const int t = blockIdx.y;
    const int co = tid & 31;

    for (int q = tid; q < NQ; q += 256) {
        int ky = q / WP;
        int col = q - ky * WP;
        int iy = 2 * oy - PAD + ky;
        int ix = col - 1;
        float4 v = make_float4(0.f, 0.f, 0.f, 0.f);
        if (iy >= 0 && iy < W && ix >= 0 && ix < W)
            v = *(const float4*)&in[(((size_t)t * W + iy) * W + ix) * 4];
        *(float4*)&in_s[q * 4] = v;
    }

    float wr[9][4];
#pragma unroll
    for (int tap = 0; tap < 9; ++tap)
#pragma unroll
        for (int j = 0; j < 4; ++j) wr[tap][j] = wg[(tap * 4 + j) * 32 + co];
    __syncthreads();

    const int g = tid >> 5;
    constexpr int NOX = (OW + 7) / 8;
    float acc[NOX];
#pragma unroll
    for (int m = 0; m < NOX; ++m) acc[m] = 0.f;
#pragma unroll
    for (int ky = 0; ky < 3; ++ky)
#pragma unroll
        for (int kx = 0; kx < 3; ++kx) {
            float w0 = wr[ky * 3 + kx][0], w1 = wr[ky * 3 + kx][1];
            float w2 = wr[ky * 3 + kx][2], w3 = wr[ky * 3 + kx][3];
#pragma unroll
            for (int m = 0; m < NOX; ++m) {
                int ox = g + 8 * m;
                if (ox < OW) {
                    int cs = 2 * ox + kx - PAD + 1;
                    float4 xi = *(const float4*)&in_s[(ky * WP + cs) * 4];
                    acc[m] += xi.x * w0 + xi.y * w1 + xi.z * w2 + xi.w * w3;
                }
            }
        }
    float b = bias[co];
#pragma unroll
    for (int m = 0; m < NOX; ++m) {
        int ox = g + 8 * m;
        if (ox < OW)
            out[(((size_t)t * OW + oy) * OW + ox) * 32 + co] = f16bits(felu(acc[m] + b));
    }
}

// ---------------- convh: f16 in (CIN=32, dot2), f16 or f32 out ----------------
template <int W, int OW, int PAD, bool F32OUT>
__global__ __launch_bounds__(256) void convh_kernel(const unsigned short* __restrict__ in,
                                                    const float* __restrict__ wg,
                                                    const float* __restrict__ bias,
                                                    void* __restrict__ outv) {
    constexpr int WP = W + 2;
    constexpr int OWH = (OW + 1) / 2;
    __shared__ __align__(16) unsigned short in_s[3][WP][32];
    __shared__ float zs[4][OW * 32];

    const int tid = threadIdx.x;
    const int oy = blockIdx.x;
    const int t = blockIdx.y;
    const int co = tid & 31;
    const int cig = (tid >> 5) & 3;
    const int oxh = tid >> 7;

    constexpr int NQ4 = 3 * WP * 4;
    uint4* in_s4 = reinterpret_cast<uint4*>(&in_s[0][0][0]);
    for (int q = tid; q < NQ4; q += 256) {
        int ky = q / (WP * 4);
        int rem = q - ky * (WP * 4);
        int col = rem >> 2, c4 = rem & 3;
        int iy = 2 * oy - PAD + ky;
        int ix = col - 1;
        uint4 v = make_uint4(0u, 0u, 0u, 0u);
        if (iy >= 0 && iy < W && ix >= 0 && ix < W)
            v = *(const uint4*)&in[(((size_t)t * W + iy) * W + ix) * 32 + c4 * 8];
        in_s4[q] = v;
    }

    unsigned int wr[9][4];
#pragma unroll
    for (int tap = 0; tap < 9; ++tap)
#pragma unroll
        for (int p = 0; p < 4; ++p)
            wr[tap][p] = packh2(wg[(tap * 32 + cig * 8 + 2 * p) * 32 + co],
                                wg[(tap * 32 + cig * 8 + 2 * p + 1) * 32 + co]);
    __syncthreads();

    float acc[OWH];
#pragma unroll
    for (int m = 0; m < OWH; ++m) acc[m] = 0.f;
#pragma unroll
    for (int ky = 0; ky < 3; ++ky)
#pragma unroll
        for (int kx = 0; kx < 3; ++kx) {
            unsigned int w0 = wr[ky * 3 + kx][0], w1 = wr[ky * 3 + kx][1];
            unsigned int w2 = wr[ky * 3 + kx][2], w3 = wr[ky * 3 + kx][3];
#pragma unroll
            for (int m = 0; m < OWH; ++m) {
                int ox = oxh * OWH + m;
                if (ox < OW) {
                    int cs = 2 * ox + kx - PAD + 1;
                    uint4 h8 = *(const uint4*)&in_s[ky][cs][cig * 8];
                    acc[m] = dot2acc(w0, h8.x, acc[m]);
                    acc[m] = dot2acc(w1, h8.y, acc[m]);
                    acc[m] = dot2acc(w2, h8.z, acc[m]);
                    acc[m] = dot2acc(w3, h8.w, acc[m]);
                }
            }
        }
#pragma unroll
    for (int m = 0; m < OWH; ++m) {
        int ox = oxh * OWH + m;
        if (ox < OW) zs[cig][ox * 32 + co] = acc[m];
    }
    __syncthreads();

    for (int idx = tid; idx < OW * 32; idx += 256) {
        float s = zs[0][idx] + zs[1][idx] + zs[2][idx] + zs[3][idx] + bias[idx & 31];
        s = felu(s);
        if constexpr (F32OUT)
            ((float*)outv)[(((size_t)t * OW + oy) * OW) * 32 + idx] = s;
        else
            ((unsigned short*)outv)[(((size_t)t * OW + oy) * OW) * 32 + idx] = f16bits(s);
    }
}

// ---------------- xpart GEMM ----------------
__global__ void gemm_kernel(const float* __restrict__ A, const float* __restrict__ Wx,
                            const float* __restrict__ bias, float* __restrict__ C) {
    __shared__ float As[32][64];
    __shared__ float Bs[32][64];
    const int bn = blockIdx.x, bm = blockIdx.y;
    const int tx = threadIdx.x, ty = threadIdx.y;
    const int tid = ty * 16 + tx;
    float acc[4][4] = {};
    for (int k0 = 0; k0 < 1152; k0 += 32) {
        {
            int r = tid >> 3;
            int c = (tid & 7) * 4;
            float4 a0 = *(const float4*)&A[(size_t)(bm * 64 + r) * 1152 + k0 + c];
            float4 a1 = *(const float4*)&A[(size_t)(bm * 64 + r + 32) * 1152 + k0 + c];
            As[c + 0][r] = a0.x; As[c + 1][r] = a0.y; As[c + 2][r] = a0.z; As[c + 3][r] = a0.w;
            As[c + 0][r + 32] = a1.x; As[c + 1][r + 32] = a1.y; As[c + 2][r + 32] = a1.z; As[c + 3][r + 32] = a1.w;
            int rb = tid >> 4;
            int cb = (tid & 15) * 4;
            *(float4*)&Bs[rb][cb] = *(const float4*)&Wx[(size_t)(k0 + rb) * 1024 + bn * 64 + cb];
            *(float4*)&Bs[rb + 16][cb] = *(const float4*)&Wx[(size_t)(k0 + rb + 16) * 1024 + bn * 64 + cb];
        }
        __syncthreads();
#pragma unroll
        for (int kk = 0; kk < 32; ++kk) {
            float4 a = *(float4*)&As[kk][ty * 4];
            float4 b = *(float4*)&Bs[kk][tx * 4];
            acc[0][0] += a.x * b.x; acc[0][1] += a.x * b.y; acc[0][2] += a.x * b.z; acc[0][3] += a.x * b.w;
            acc[1][0] += a.y * b.x; acc[1][1] += a.y * b.y; acc[1][2] += a.y * b.z; acc[1][3] += a.y * b.w;
            acc[2][0] += a.z * b.x; acc[2][1] += a.z * b.y; acc[2][2] += a.z * b.z; acc[2][3] += a.z * b.w;
            acc[3][0] += a.w * b.x; acc[3][1] += a.w * b.y; acc[3][2] += a.w * b.z; acc[3][3] += a.w * b.w;
        }
        __syncthreads();
    }
#pragma unroll
    for (int i = 0; i < 4; ++i) {
        int row = bm * 64 + ty * 4 + i;
#pragma unroll
        for (int j = 0; j < 4; ++j) {
            int col = bn * 64 + tx * 4 + j;
            C[(size_t)row * 1024 + col] = acc[i][j] + bias[col];
        }
    }
}

// ---------------- LSTM lstm9: in-wave k-split + lstm7 weight split, 1 barrier/step ----
// 8 waves; wave w owns units [32w,32w+32). Lane l: k-half s=l>>5, unit u0=32w+(l&31).
// Thread computes all 4 gate partials for u0 over k in [128s,128s+128): per gate
// 12 pairs from LDS (wl[tid][52], 48 used) + 52 pairs in registers (208 uints; the
// ~half beyond the 128-VGPR split sits in AGPRs with accvgpr-copy cost — structural,
// see r12: VOP3P can't read AGPRs directly). Partner partial at lane^32 (same wave)
// -> 4x __shfl_xor combine: no zsm, ONE lgkm-only barrier/step (hpk double-buffered;
// reads of buf b at step t and writes of b at t+1 are barrier-separated).
__global__ __launch_bounds__(512) void lstm9_kernel(const float* __restrict__ lstm_w,
                                                    const float* __restrict__ xpart,
                                                    const float* __restrict__ c_in,
                                                    const float* __restrict__ h_in,
                                                    float* __restrict__ hs_out) {
    __shared__ __align__(16) unsigned int wl[512][52];      // 48 used per row
    __shared__ __align__(16) unsigned short hpk[2][256];    // h f16, double-buffered

    const int tid = threadIdx.x;
    const int wv = tid >> 6;
    const int l = tid & 63;
    const int s = l >> 5;                  // k-half
    const int u0 = (wv << 5) + (l & 31);   // unit

    // stage weights: gate q, pair p -> W[1152 + 128s + 2p (+1)][256q + u0]
    for (int q = 0; q < 4; ++q)
        for (int p = 0; p < 12; ++p)
            wl[tid][q * 12 + p] = packh2(
                lstm_w[(size_t)(1152 + 128 * s + 2 * p) * 1024 + (q << 8) + u0],
                lstm_w[(size_t)(1152 + 128 * s + 2 * p + 1) * 1024 + (q << 8) + u0]);
    unsigned int wreg[4][52];
#pragma unroll
    for (int q = 0; q < 4; ++q)
        for (int p = 12; p < 64; ++p)
            wreg[q][p - 12] = packh2(
                lstm_w[(size_t)(1152 + 128 * s + 2 * p) * 1024 + (q << 8) + u0],
                lstm_w[(size_t)(1152 + 128 * s + 2 * p + 1) * 1024 + (q << 8) + u0]);

    float c_state = c_in[u0];              // redundant in both halves
    if (tid < 256) hpk[0][tid] = f16bits(h_in[tid]);
    __syncthreads();

    float xp0 = xpart[u0], xp1 = xpart[256 + u0], xp2 = xpart[512 + u0], xp3 = xpart[768 + u0];

    for (int t = 0; t < 2048; ++t) {
        const int cur = t & 1;
        const uint4* hq = reinterpret_cast<const uint4*>(&hpk[cur][s << 7]);

        float a0 = 0.f, a1 = 0.f, a2 = 0.f, a3 = 0.f;
        {   // LDS-weight chunks: pairs 0..11 = h chunks 0..2
            uint4 hA = hq[0], hB = hq[1], hC = hq[2];
            uint4 w0a = *(const uint4*)&wl[tid][0];
            uint4 w0b = *(const uint4*)&wl[tid][4];
            uint4 w0c = *(const uint4*)&wl[tid][8];
            a0 = dot2acc(w0a.x, hA.x, a0); a0 = dot2acc(w0a.y, hA.y, a0);
            a0 = dot2acc(w0a.z, hA.z, a0); a0 = dot2acc(w0a.w, hA.w, a0);
            a0 = dot2acc(w0b.x, hB.x, a0); a0 = dot2acc(w0b.y, hB.y, a0);
            a0 = dot2acc(w0b.z, hB.z, a0); a0 = dot2acc(w0b.w, hB.w, a0);
            a0 = dot2acc(w0c.x, hC.x, a0); a0 = dot2acc(w0c.y, hC.y, a0);
            a0 = dot2acc(w0c.z, hC.z, a0); a0 = dot2acc(w0c.w, hC.w, a0);
            uint4 w1a = *(const uint4*)&wl[tid][12];
            uint4 w1b = *(const uint4*)&wl[tid][16];
            uint4 w1c = *(const uint4*)&wl[tid][20];
            a1 = dot2acc(w1a.x, hA.x, a1); a1 = dot2acc(w1a.y, hA.y, a1);
            a1 = dot2acc(w1a.z, hA.z, a1); a1 = dot2acc(w1a.w, hA.w, a1);
            a1 = dot2acc(w1b.x, hB.x, a1); a1 = dot2acc(w1b.y, hB.y, a1);
            a1 = dot2acc(w1b.z, hB.z, a1); a1 = dot2acc(w1b.w, hB.w, a1);
            a1 = dot2acc(w1c.x, hC.x, a1); a1 = dot2acc(w1c.y, hC.y, a1);
            a1 = dot2acc(w1c.z, hC.z, a1); a1 = dot2acc(w1c.w, hC.w, a1);
            uint4 w2a = *(const uint4*)&wl[tid][24];
            uint4 w2b = *(const uint4*)&wl[tid][28];
            uint4 w2c = *(const uint4*)&wl[tid][32];
            a2 = dot2acc(w2a.x, hA.x, a2); a2 = dot2acc(w2a.y, hA.y, a2);
            a2 = dot2acc(w2a.z, hA.z, a2); a2 = dot2acc(w2a.w, hA.w, a2);
            a2 = dot2acc(w2b.x, hB.x, a2); a2 = dot2acc(w2b.y, hB.y, a2);
            a2 = dot2acc(w2b.z, hB.z, a2); a2 = dot2acc(w2b.w, hB.w, a2);
            a2 = dot2acc(w2c.x, hC.x, a2); a2 = dot2acc(w2c.y, hC.y, a2);
            a2 = dot2acc(w2c.z, hC.z, a2); a2 = dot2acc(w2c.w, hC.w, a2);
            uint4 w3a = *(const uint4*)&wl[tid][36];
            uint4 w3b = *(const uint4*)&wl[tid][40];
            uint4 w3c = *(const uint4*)&wl[tid][44];
            a3 = dot2acc(w3a.x, hA.x, a3); a3 = dot2acc(w3a.y, hA.y, a3);
            a3 = dot2acc(w3a.z, hA.z, a3); a3 = dot2acc(w3a.w, hA.w, a3);
            a3 = dot2acc(w3b.x, hB.x, a3); a3 = dot2acc(w3b.y, hB.y, a3);
            a3 = dot2acc(w3b.z, hB.z, a3); a3 = dot2acc(w3b.w, hB.w, a3);
            a3 = dot2acc(w3c.x, hC.x, a3); a3 = dot2acc(w3c.y, hC.y, a3);
            a3 = dot2acc(w3c.z, hC.z, a3); a3 = dot2acc(w3c.w, hC.w, a3);
        }
#pragma unroll
        for (int c = 3; c < 16; ++c) {     // register chunks: pairs 12..63
            uint4 h4 = hq[c];
            const int r = 4 * (c - 3);
            a0 = dot2acc(wreg[0][r + 0], h4.x, a0); a0 = dot2acc(wreg[0][r + 1], h4.y, a0);
            a0 = dot2acc(wreg[0][r + 2], h4.z, a0); a0 = dot2acc(wreg[0][r + 3], h4.w, a0);
            a1 = dot2acc(wreg[1][r + 0], h4.x, a1); a1 = dot2acc(wreg[1][r + 1], h4.y, a1);
            a1 = dot2acc(wreg[1][r + 2], h4.z, a1); a1 = dot2acc(wreg[1][r + 3], h4.w, a1);
            a2 = dot2acc(wreg[2][r + 0], h4.x, a2); a2 = dot2acc(wreg[2][r + 1], h4.y, a2);
            a2 = dot2acc(wreg[2][r + 2], h4.z, a2); a2 = dot2acc(wreg[2][r + 3], h4.w, a2);
            a3 = dot2acc(wreg[3][r + 0], h4.x, a3); a3 = dot2acc(wreg[3][r + 1], h4.y, a3);
            a3 = dot2acc(wreg[3][r + 2], h4.z, a3); a3 = dot2acc(wreg[3][r + 3], h4.w, a3);
        }

        // prefetch next xpart row
        float xn0 = 0.f, xn1 = 0.f, xn2 = 0.f, xn3 = 0.f;
        if (t + 1 < 2048) {
            const float* xr = &xpart[(size_t)(t + 1) * 1024];
            xn0 = xr[u0]; xn1 = xr[256 + u0]; xn2 = xr[512 + u0]; xn3 = xr[768 + u0];
        }

        // combine k-halves in-wave (partner = lane ^ 32)
        float zi = a0 + __shfl_xor(a0, 32, 64) + xp0;
        float zj = a1 + __shfl_xor(a1, 32, 64) + xp1;
        float zf = a2 + __shfl_xor(a2, 32, 64) + xp2;
        float zo = a3 + __shfl_xor(a3, 32, 64) + xp3;

        c_state = c_state * fsig(zf + 1.0f) + fsig(zi) * ftanh(zj);
        float h = ftanh(c_state) * fsig(zo);
        if (s == 0) {
            hs_out[(size_t)t * 256 + u0] = h;
            hpk[cur ^ 1][u0] = f16bits(h);
        }

        asm volatile("s_waitcnt lgkmcnt(0)\n\ts_barrier" ::: "memory");
        xp0 = xn0; xp1 = xn1; xp2 = xn2; xp3 = xn3;
    }
}

// ---------------- logits ----------------
__global__ void logits_kernel(const float* __restrict__ hs, const float* __restrict__ fc_w,
                              const float* __restrict__ fc_b, float* __restrict__ out) {
    int idx = blockIdx.x * 256 + threadIdx.x;
    if (idx >= 2048 * 18) return;
    int t = idx / 18, n = idx % 18;
    float acc = fc_b[n];
    const float* hrow = hs + (size_t)t * 256;
#pragma unroll 4
    for (int k = 0; k < 256; ++k) acc += hrow[k] * fc_w[k * 18 + n];
    out[idx] = acc;
}

// ---------------- launch ----------------
extern "C" void kernel_launch(void* const* d_in, const int* in_sizes, int n_in,
                              void* d_out, int out_size, void* d_ws, size_t ws_size,
                              hipStream_t stream) {
    const float* x   = (const float*)d_in[0];
    const float* w0  = (const float*)d_in[1];
    const float* b0  = (const float*)d_in[2];
    const float* w1  = (const float*)d_in[3];
    const float* b1  = (const float*)d_in[4];
    const float* w2  = (const float*)d_in[5];
    const float* b2  = (const float*)d_in[6];
    const float* w3  = (const float*)d_in[7];
    const float* b3  = (const float*)d_in[8];
    const float* lw  = (const float*)d_in[9];
    const float* lb  = (const float*)d_in[10];
    const float* fcw = (const float*)d_in[11];
    const float* fcb = (const float*)d_in[12];
    const float* cin = (const float*)d_in[13];
    const float* hin = (const float*)d_in[14];

    float* outp = (float*)d_out;
    float* hs_out = outp + 2048 * 18;

    const size_t FIXED_B = ((size_t)2048 * 1152 + (size_t)2048 * 1024) * 4;
    const size_t PERT_B = ((size_t)56448 + 14112 + 3872) * 2;

    int C = 128;
    const int cands[5] = {2048, 1024, 512, 256, 128};
    for (int i = 0; i < 5; ++i) {
        if (FIXED_B + (size_t)cands[i] * PERT_B <= ws_size) { C = cands[i]; break; }
    }

    float* feats = (float*)d_ws;
    float* xpart = feats + (size_t)2048 * 1152;
    unsigned short* c0buf = (unsigned short*)(xpart + (size_t)2048 * 1024);
    unsigned short* c1buf = c0buf + (size_t)C * 56448;
    unsigned short* c2buf = c1buf + (size_t)C * 14112;

    for (int t0 = 0; t0 < 2048; t0 += C) {
        const float* xin = x + (size_t)t0 * 84 * 84 * 4;
        conv0_kernel<<<dim3(42, C), 256, 0, stream>>>(xin, w0, b0, c0buf);
        convh_kernel<42, 21, 0, false><<<dim3(21, C), 256, 0, stream>>>(c0buf, w1, b1, c1buf);
        convh_kernel<21, 11, 1, false><<<dim3(11, C), 256, 0, stream>>>(c1buf, w2, b2, c2buf);
        convh_kernel<11, 6, 1, true><<<dim3(6, C), 256, 0, stream>>>(c2buf, w3, b3,
                                                                     feats + (size_t)t0 * 1152);
    }

    gemm_kernel<<<dim3(16, 32), dim3(16, 16), 0, stream>>>(feats, lw, lb, xpart);
    lstm9_kernel<<<1, 512, 0, stream>>>(lw, xpart, cin, hin, hs_out);
    logits_kernel<<<144, 256, 0, stream>>>(hs_out, fcw, fcb, outp);
}